// Round 17
// baseline (478.174 us; speedup 1.0000x reference)
//
#include <hip/hip_runtime.h>
#include <hip/hip_bf16.h>
#include <cstdint>

typedef __attribute__((ext_vector_type(4))) float f32x4;
typedef __attribute__((ext_vector_type(2))) long long2_t;

#define DIM 256
#define TINV 10.0f
#define EXP2C 14.426950408889634f   // TINV * log2(e)
#define BM 128
#define BN 128
#define BK 64
#define NT 64                        // N/BN
#define T_TILES 2080                 // NT*(NT+1)/2
#define NFIN 32                      // last-32 tickets perform the reduce

// ONE dispatch. Phase 1: claim/ready strip normalization (spinner only waits
// on a RESIDENT claimer => deadlock-free). Phase 2: R16 gemm body verbatim.
// Phase 3: last-32-ticket blocks reduce 256-row slices; ticket2==31 finalizes.
__launch_bounds__(512, 8)
__global__ void nt_all(const float* __restrict__ y, uint8_t* __restrict__ ynq,
                       float* __restrict__ P, float* __restrict__ posterm,
                       float* __restrict__ blockpart, int* __restrict__ flags,
                       unsigned* __restrict__ cnt, unsigned* __restrict__ cnt2,
                       float* __restrict__ out, int N) {
    const int nt = NT;
    const int T = T_TILES;
    // bijective XCD-chunked swizzle (m204)
    int orig = blockIdx.x;
    int q = T >> 3, r = T & 7;
    int xcd = orig & 7, loc = orig >> 3;
    int t = (xcd < r ? xcd * (q + 1) : r * (q + 1) + (xcd - r) * q) + loc;
    // triangular index -> (by, bx), by <= bx (from bottom-right corner)
    int s = T - 1 - t;
    float f = sqrtf(8.0f * (float)s + 1.0f);
    int j = (int)((f - 1.0f) * 0.5f);
    while ((j + 1) * (j + 2) / 2 <= s) ++j;
    while (j * (j + 1) / 2 > s) --j;
    int k = s - j * (j + 1) / 2;
    int by = nt - 1 - j, bx = nt - 1 - k;

    __shared__ __align__(16) uint8_t As[BM * BK];    // 8 KB
    __shared__ __align__(16) uint8_t Bs[BN * BK];    // 8 KB
    __shared__ float rowpart[4][BM];                 // 2 KB
    __shared__ float colpart[2][BN];                 // 1 KB
    __shared__ float rparts[8];
    __shared__ unsigned sh_u;

    int r0 = by * BM, c0 = bx * BN;
    int tid = threadIdx.x;
    int wave = tid >> 6, lane = tid & 63;
    int wr = wave >> 2, wc = wave & 3;
    int l16 = lane & 15, lg = lane >> 4;

    // ---------------- Phase 1: ensure strips by, bx are normalized ----------
#pragma unroll
    for (int pass = 0; pass < 2; ++pass) {
        if (pass == 1 && bx == by) break;               // block-uniform
        int sidx = (pass == 0) ? by : bx;
        if (tid == 0) sh_u = (unsigned)atomicCAS(&flags[sidx], 0, 1);
        __syncthreads();
        unsigned st = sh_u;
        if (st == 0) {
            // We claimed: normalize rows [sidx*128, +128); wave w does 16 rows.
            for (int rr = 0; rr < 16; ++rr) {
                int row = sidx * 128 + wave * 16 + rr;
                float4 v = ((const float4*)(y + (size_t)row * DIM))[lane];
                float ssq = v.x * v.x + v.y * v.y + v.z * v.z + v.w * v.w;
#pragma unroll
                for (int off = 1; off < 64; off <<= 1) ssq += __shfl_xor(ssq, off);
                float inv = 1.0f / fmaxf(sqrtf(ssq), 1e-8f);
                int w = __builtin_amdgcn_cvt_pk_fp8_f32(v.x * inv, v.y * inv, 0, false);
                w = __builtin_amdgcn_cvt_pk_fp8_f32(v.z * inv, v.w * inv, w, true);
                // pair-interleaved store (R16 format): unit u -> byte 16(u&3)+8(u>>2)
                int u_row = lane >> 1;
                int addr = (u_row >> 3) * 64 + (((u_row & 7) & 3) << 4)
                           + (((u_row & 7) >> 2) << 3) + ((lane & 1) << 2);
                *(int*)(ynq + (size_t)row * DIM + addr) = w;
            }
            __syncthreads();
            if (tid == 0) { __threadfence(); atomicExch(&flags[sidx], 2); }
        } else if (st == 1) {
            if (tid == 0)
                while (atomicAdd((int*)&flags[sidx], 0) != 2)
                    __builtin_amdgcn_s_sleep(8);
            __syncthreads();
        }
        // st == 2: already ready
    }
    __threadfence();       // acquire: cross-XCD visibility of ynq (all threads)
    __syncthreads();

    // ---------------- Phase 2: fp8 sim-GEMM (R16 body verbatim) -------------
    int srow = tid >> 2, scc = tid & 3;
    int sgc = scc ^ (srow & 3);
    int slot16 = (lg ^ (l16 & 3)) * 16;

    int arow[4], brow[2];
#pragma unroll
    for (int m = 0; m < 4; ++m) arow[m] = (wr * 64 + m * 16 + l16) * BK;
#pragma unroll
    for (int n = 0; n < 2; ++n) brow[n] = (wc * 32 + n * 16 + l16) * BK;

    f32x4 acc[4][2] = {};

    for (int k0 = 0; k0 < DIM; k0 += BK) {
        if (k0) __syncthreads();
        {
            const uint8_t* srcA = ynq + (size_t)(r0 + srow) * DIM + k0 + sgc * 16;
            __builtin_amdgcn_global_load_lds(
                (const __attribute__((address_space(1))) uint32_t*)srcA,
                (__attribute__((address_space(3))) uint32_t*)(As + wave * 1024), 16, 0, 0);
            const uint8_t* srcB = ynq + (size_t)(c0 + srow) * DIM + k0 + sgc * 16;
            __builtin_amdgcn_global_load_lds(
                (const __attribute__((address_space(1))) uint32_t*)srcB,
                (__attribute__((address_space(3))) uint32_t*)(Bs + wave * 1024), 16, 0, 0);
        }
        __syncthreads();

        long2_t a2[4];
#pragma unroll
        for (int m = 0; m < 4; ++m)
            a2[m] = *(const long2_t*)(As + arow[m] + slot16);
#pragma unroll
        for (int kk = 0; kk < 2; ++kk) {
            long bv[2];
#pragma unroll
            for (int n = 0; n < 2; ++n)
                bv[n] = *(const long*)(Bs + brow[n] + slot16 + kk * 8);
#pragma unroll
            for (int m = 0; m < 4; ++m) {
                long am = kk ? a2[m].y : a2[m].x;
#pragma unroll
                for (int n = 0; n < 2; ++n)
                    acc[m][n] = __builtin_amdgcn_mfma_f32_16x16x32_fp8_fp8(
                        am, bv[n], acc[m][n], 0, 0, 0);
            }
        }
    }

    // Epilogue (R16 verbatim). C/D layout (m89): col=lane&15, row=lg*4+reg.
    bool diag = (by == bx);
    float colacc0 = 0.0f, colacc1 = 0.0f;
    float rp[16];
#pragma unroll
    for (int m = 0; m < 4; ++m) {
#pragma unroll
        for (int r2 = 0; r2 < 4; ++r2) {
            int grow = r0 + wr * 64 + m * 16 + lg * 4 + r2;
            float s0, s1;
            {
                float S = acc[m][0][r2];
                float e = __builtin_amdgcn_exp2f(S * EXP2C);
                if (diag) {
                    int gcol = c0 + wc * 32 + l16;
                    if (gcol == grow) e = 0.0f;
                    if (gcol == (grow ^ 1)) posterm[grow] = -S * TINV;
                }
                s0 = e; colacc0 += e;
            }
            {
                float S = acc[m][1][r2];
                float e = __builtin_amdgcn_exp2f(S * EXP2C);
                if (diag) {
                    int gcol = c0 + wc * 32 + 16 + l16;
                    if (gcol == grow) e = 0.0f;
                    if (gcol == (grow ^ 1)) posterm[grow] = -S * TINV;
                }
                s1 = e; colacc1 += e;
            }
            rp[m * 4 + r2] = s0 + s1;
        }
    }
    int b0 = l16 & 1, b1 = (l16 >> 1) & 1, b2_ = (l16 >> 2) & 1, b3 = (l16 >> 3) & 1;
    float t8[8];
#pragma unroll
    for (int i = 0; i < 8; ++i) {
        float send = b0 ? rp[2 * i] : rp[2 * i + 1];
        float keep = b0 ? rp[2 * i + 1] : rp[2 * i];
        t8[i] = keep + __shfl_xor(send, 1);
    }
    float t4[4];
#pragma unroll
    for (int i = 0; i < 4; ++i) {
        float send = b1 ? t8[2 * i] : t8[2 * i + 1];
        float keep = b1 ? t8[2 * i + 1] : t8[2 * i];
        t4[i] = keep + __shfl_xor(send, 2);
    }
    float t2[2];
#pragma unroll
    for (int i = 0; i < 2; ++i) {
        float send = b2_ ? t4[2 * i] : t4[2 * i + 1];
        float keep = b2_ ? t4[2 * i + 1] : t4[2 * i];
        t2[i] = keep + __shfl_xor(send, 4);
    }
    {
        float send = b3 ? t2[0] : t2[1];
        float keep = b3 ? t2[1] : t2[0];
        float rsum = keep + __shfl_xor(send, 8);
        int row_w = ((l16 >> 2) & 3) * 16 + lg * 4 + (l16 & 3);
        rowpart[wc][wr * 64 + row_w] = rsum;
    }
    colacc0 += __shfl_xor(colacc0, 16); colacc0 += __shfl_xor(colacc0, 32);
    colacc1 += __shfl_xor(colacc1, 16); colacc1 += __shfl_xor(colacc1, 32);
    if (!diag && lane < 16) {
        colpart[wr][wc * 32 + lane] = colacc0;
        colpart[wr][wc * 32 + 16 + lane] = colacc1;
    }
    __syncthreads();
    if (tid < BM) {
        P[(size_t)bx * N + r0 + tid] =
            rowpart[0][tid] + rowpart[1][tid] + rowpart[2][tid] + rowpart[3][tid];
    } else if (tid < 2 * BM && !diag) {
        int lcol = tid - BM;
        P[(size_t)by * N + c0 + lcol] = colpart[0][lcol] + colpart[1][lcol];
    }

    // ---------------- Phase 3: last-32 tickets reduce + finalize ------------
    __syncthreads();
    if (tid == 0) { __threadfence(); sh_u = atomicAdd(cnt, 1u); }
    __syncthreads();
    unsigned ticket = sh_u;
    if (ticket < (unsigned)(T - NFIN)) return;          // block-uniform exit
    if (tid == 0)
        while (atomicAdd(cnt, 0u) < (unsigned)T) __builtin_amdgcn_s_sleep(8);
    __syncthreads();
    __threadfence();                                    // acquire: P visible

    int slice = (int)ticket - (T - NFIN);               // 0..31
    float v = 0.0f;
    if (tid < 256) {
        int row = slice * 256 + tid;
        float ssum = 0.0f;
#pragma unroll
        for (int jj = 0; jj < NT; ++jj) ssum += P[(size_t)jj * N + row];
        v = posterm[row] + logf(ssum);
    }
#pragma unroll
    for (int off = 1; off < 64; off <<= 1) v += __shfl_xor(v, off);
    if (lane == 0) rparts[wave] = v;
    __syncthreads();
    if (tid == 0) {
        float bp = 0.0f;
#pragma unroll
        for (int w2 = 0; w2 < 8; ++w2) bp += rparts[w2];
        blockpart[slice] = bp;
        __threadfence();
        sh_u = atomicAdd(cnt2, 1u);
    }
    __syncthreads();
    if (sh_u == NFIN - 1) {                             // this block is last
        __threadfence();
        if (wave == 0) {
            float w2 = (lane < NFIN)
                           ? __hip_atomic_load(&blockpart[lane], __ATOMIC_RELAXED,
                                               __HIP_MEMORY_SCOPE_AGENT)
                           : 0.0f;
#pragma unroll
            for (int off = 1; off < 64; off <<= 1) w2 += __shfl_xor(w2, off);
            if (lane == 0) out[0] = w2 / (float)N;
        }
    }
}

extern "C" void kernel_launch(void* const* d_in, const int* in_sizes, int n_in,
                              void* d_out, int out_size, void* d_ws, size_t ws_size,
                              hipStream_t stream) {
    const float* y = (const float*)d_in[0];
    int N = in_sizes[0] / DIM;                 // 8192
    uint8_t* ynq = (uint8_t*)d_ws;             // 2 MB (pair-interleaved fp8)
    float* posterm = (float*)((char*)d_ws + (size_t)N * DIM);   // 32 KB
    float* P = posterm + N;                    // 64*N f32 = 2 MB
    float* blockpart = P + (size_t)NT * N;     // NFIN f32
    int* flags = (int*)(blockpart + NFIN);     // 64 ints
    unsigned* cnt = (unsigned*)(flags + NT);   // 1
    unsigned* cnt2 = cnt + 1;                  // 1
    float* out = (float*)d_out;

    // zero per-call control state (flags + cnt + cnt2), capture-legal
    hipMemsetAsync(flags, 0, (NT + 2) * sizeof(int), stream);
    nt_all<<<T_TILES, 512, 0, stream>>>(y, ynq, P, posterm, blockpart,
                                        flags, cnt, cnt2, out, N);
}

// Round 18
// 105.675 us; speedup vs baseline: 4.5249x; 4.5249x over previous
//
#include <hip/hip_runtime.h>
#include <hip/hip_bf16.h>
#include <cstdint>

typedef __attribute__((ext_vector_type(4))) float f32x4;
typedef __attribute__((ext_vector_type(2))) long long2_t;

#define DIM 256
#define TINV 10.0f
#define EXP2C 14.426950408889634f   // TINV * log2(e)
#define BM 128
#define BN 128
#define BK 64
#define NT 64                        // N/BN
#define T_TILES 2080                 // NT*(NT+1)/2
#define NFIN 32                      // last-32 tickets perform the reduce

// Kernel 1: row-normalize y (f32) -> fp8 e4m3, PAIR-INTERLEAVED (R16 format):
// within each 64B row-block, 8B-unit u lands at byte 16*(u&3)+8*(u>>2).
__global__ void nt_normalize(const float* __restrict__ y, uint8_t* __restrict__ ynq,
                             int N) {
    int tid = threadIdx.x;
    int wave = tid >> 6, lane = tid & 63;
    int row = blockIdx.x * 4 + wave;
    float4 v = ((const float4*)(y + (size_t)row * DIM))[lane];
    float ss = v.x * v.x + v.y * v.y + v.z * v.z + v.w * v.w;
#pragma unroll
    for (int off = 1; off < 64; off <<= 1) ss += __shfl_xor(ss, off);
    float inv = 1.0f / fmaxf(sqrtf(ss), 1e-8f);
    int w = __builtin_amdgcn_cvt_pk_fp8_f32(v.x * inv, v.y * inv, 0, false);
    w = __builtin_amdgcn_cvt_pk_fp8_f32(v.z * inv, v.w * inv, w, true);
    int u_row = lane >> 1;
    int addr = (u_row >> 3) * 64 + (((u_row & 7) & 3) << 4) + (((u_row & 7) >> 2) << 3)
               + ((lane & 1) << 2);
    *(int*)(ynq + (size_t)row * DIM + addr) = w;
}

// Kernel 2: fp8 sim-GEMM (R16 body verbatim) + FUSED reduce/final tail.
// After P stores each block takes a ticket; the last NFIN=32 spin (only on
// each other — all resident => deadlock-free, protocol verified in R17),
// reduce 256-row slices, and the last of the 32 writes out[0].
// amdgpu_waves_per_eu(8,8): max 8 waves/EU => no payoff for the backend's
// occupancy heuristic to shrink VGPRs below 64 (R13/R17 spilled acc at 32).
__attribute__((amdgpu_waves_per_eu(8, 8)))
__launch_bounds__(512)
__global__ void nt_gemm_red(const uint8_t* __restrict__ ynq, float* __restrict__ P,
                            float* __restrict__ posterm, float* __restrict__ blockpart,
                            unsigned* __restrict__ cnt, unsigned* __restrict__ cnt2,
                            float* __restrict__ out, int N) {
    const int nt = NT;
    const int T = T_TILES;
    // bijective XCD-chunked swizzle (m204)
    int orig = blockIdx.x;
    int q = T >> 3, r = T & 7;
    int xcd = orig & 7, loc = orig >> 3;
    int t = (xcd < r ? xcd * (q + 1) : r * (q + 1) + (xcd - r) * q) + loc;
    // triangular index -> (by, bx), by <= bx (from bottom-right corner)
    int s = T - 1 - t;
    float f = sqrtf(8.0f * (float)s + 1.0f);
    int j = (int)((f - 1.0f) * 0.5f);
    while ((j + 1) * (j + 2) / 2 <= s) ++j;
    while (j * (j + 1) / 2 > s) --j;
    int k = s - j * (j + 1) / 2;
    int by = nt - 1 - j, bx = nt - 1 - k;

    __shared__ __align__(16) uint8_t As[BM * BK];    // 8 KB
    __shared__ __align__(16) uint8_t Bs[BN * BK];    // 8 KB
    __shared__ float rowpart[4][BM];                 // 2 KB
    __shared__ float colpart[2][BN];                 // 1 KB
    __shared__ float rparts[8];
    __shared__ unsigned sh_u;

    int r0 = by * BM, c0 = bx * BN;
    int tid = threadIdx.x;
    int wave = tid >> 6, lane = tid & 63;
    int wr = wave >> 2, wc = wave & 3;
    int l16 = lane & 15, lg = lane >> 4;

    int srow = tid >> 2, scc = tid & 3;
    int sgc = scc ^ (srow & 3);
    int slot16 = (lg ^ (l16 & 3)) * 16;

    int arow[4], brow[2];
#pragma unroll
    for (int m = 0; m < 4; ++m) arow[m] = (wr * 64 + m * 16 + l16) * BK;
#pragma unroll
    for (int n = 0; n < 2; ++n) brow[n] = (wc * 32 + n * 16 + l16) * BK;

    f32x4 acc[4][2] = {};

    for (int k0 = 0; k0 < DIM; k0 += BK) {
        if (k0) __syncthreads();
        {
            const uint8_t* srcA = ynq + (size_t)(r0 + srow) * DIM + k0 + sgc * 16;
            __builtin_amdgcn_global_load_lds(
                (const __attribute__((address_space(1))) uint32_t*)srcA,
                (__attribute__((address_space(3))) uint32_t*)(As + wave * 1024), 16, 0, 0);
            const uint8_t* srcB = ynq + (size_t)(c0 + srow) * DIM + k0 + sgc * 16;
            __builtin_amdgcn_global_load_lds(
                (const __attribute__((address_space(1))) uint32_t*)srcB,
                (__attribute__((address_space(3))) uint32_t*)(Bs + wave * 1024), 16, 0, 0);
        }
        __syncthreads();

        long2_t a2[4];
#pragma unroll
        for (int m = 0; m < 4; ++m)
            a2[m] = *(const long2_t*)(As + arow[m] + slot16);
#pragma unroll
        for (int kk = 0; kk < 2; ++kk) {
            long bv[2];
#pragma unroll
            for (int n = 0; n < 2; ++n)
                bv[n] = *(const long*)(Bs + brow[n] + slot16 + kk * 8);
#pragma unroll
            for (int m = 0; m < 4; ++m) {
                long am = kk ? a2[m].y : a2[m].x;
#pragma unroll
                for (int n = 0; n < 2; ++n)
                    acc[m][n] = __builtin_amdgcn_mfma_f32_16x16x32_fp8_fp8(
                        am, bv[n], acc[m][n], 0, 0, 0);
            }
        }
    }

    // Epilogue (R16 verbatim). C/D layout (m89): col=lane&15, row=lg*4+reg.
    bool diag = (by == bx);
    float colacc0 = 0.0f, colacc1 = 0.0f;
    float rp[16];
#pragma unroll
    for (int m = 0; m < 4; ++m) {
#pragma unroll
        for (int r2 = 0; r2 < 4; ++r2) {
            int grow = r0 + wr * 64 + m * 16 + lg * 4 + r2;
            float s0, s1;
            {
                float S = acc[m][0][r2];
                float e = __builtin_amdgcn_exp2f(S * EXP2C);
                if (diag) {
                    int gcol = c0 + wc * 32 + l16;
                    if (gcol == grow) e = 0.0f;
                    if (gcol == (grow ^ 1)) posterm[grow] = -S * TINV;
                }
                s0 = e; colacc0 += e;
            }
            {
                float S = acc[m][1][r2];
                float e = __builtin_amdgcn_exp2f(S * EXP2C);
                if (diag) {
                    int gcol = c0 + wc * 32 + 16 + l16;
                    if (gcol == grow) e = 0.0f;
                    if (gcol == (grow ^ 1)) posterm[grow] = -S * TINV;
                }
                s1 = e; colacc1 += e;
            }
            rp[m * 4 + r2] = s0 + s1;
        }
    }
    int b0 = l16 & 1, b1 = (l16 >> 1) & 1, b2_ = (l16 >> 2) & 1, b3 = (l16 >> 3) & 1;
    float t8[8];
#pragma unroll
    for (int i = 0; i < 8; ++i) {
        float send = b0 ? rp[2 * i] : rp[2 * i + 1];
        float keep = b0 ? rp[2 * i + 1] : rp[2 * i];
        t8[i] = keep + __shfl_xor(send, 1);
    }
    float t4[4];
#pragma unroll
    for (int i = 0; i < 4; ++i) {
        float send = b1 ? t8[2 * i] : t8[2 * i + 1];
        float keep = b1 ? t8[2 * i + 1] : t8[2 * i];
        t4[i] = keep + __shfl_xor(send, 2);
    }
    float t2[2];
#pragma unroll
    for (int i = 0; i < 2; ++i) {
        float send = b2_ ? t4[2 * i] : t4[2 * i + 1];
        float keep = b2_ ? t4[2 * i + 1] : t4[2 * i];
        t2[i] = keep + __shfl_xor(send, 4);
    }
    {
        float send = b3 ? t2[0] : t2[1];
        float keep = b3 ? t2[1] : t2[0];
        float rsum = keep + __shfl_xor(send, 8);
        int row_w = ((l16 >> 2) & 3) * 16 + lg * 4 + (l16 & 3);
        rowpart[wc][wr * 64 + row_w] = rsum;
    }
    colacc0 += __shfl_xor(colacc0, 16); colacc0 += __shfl_xor(colacc0, 32);
    colacc1 += __shfl_xor(colacc1, 16); colacc1 += __shfl_xor(colacc1, 32);
    if (!diag && lane < 16) {
        colpart[wr][wc * 32 + lane] = colacc0;
        colpart[wr][wc * 32 + 16 + lane] = colacc1;
    }
    __syncthreads();
    if (tid < BM) {
        P[(size_t)bx * N + r0 + tid] =
            rowpart[0][tid] + rowpart[1][tid] + rowpart[2][tid] + rowpart[3][tid];
    } else if (tid < 2 * BM && !diag) {
        int lcol = tid - BM;
        P[(size_t)by * N + c0 + lcol] = colpart[0][lcol] + colpart[1][lcol];
    }

    // ------------- Fused reduce/final tail (last-NFIN tickets) -------------
    __syncthreads();
    if (tid == 0) { __threadfence(); sh_u = atomicAdd(cnt, 1u); }
    __syncthreads();
    unsigned ticket = sh_u;
    if (ticket < (unsigned)(T - NFIN)) return;          // block-uniform exit
    if (tid == 0) {
        while (__hip_atomic_load(cnt, __ATOMIC_RELAXED, __HIP_MEMORY_SCOPE_AGENT)
               < (unsigned)T)
            __builtin_amdgcn_s_sleep(8);
        __threadfence();                                // acquire: P visible
    }
    __syncthreads();

    int slice = (int)ticket - (T - NFIN);               // 0..31
    float v = 0.0f;
    if (tid < 256) {
        int row = slice * 256 + tid;
        float ssum = 0.0f;
#pragma unroll
        for (int jj = 0; jj < NT; ++jj) ssum += P[(size_t)jj * N + row];
        v = posterm[row] + logf(ssum);
    }
#pragma unroll
    for (int off = 1; off < 64; off <<= 1) v += __shfl_xor(v, off);
    if (lane == 0) rparts[wave] = v;
    __syncthreads();
    if (tid == 0) {
        float bp = 0.0f;
#pragma unroll
        for (int w2 = 0; w2 < 8; ++w2) bp += rparts[w2];
        blockpart[slice] = bp;
        __threadfence();
        sh_u = atomicAdd(cnt2, 1u);
    }
    __syncthreads();
    if (sh_u == NFIN - 1 && wave == 0) {                // this block is last
        __threadfence();
        float w2 = (lane < NFIN)
                       ? __hip_atomic_load(&blockpart[lane], __ATOMIC_RELAXED,
                                           __HIP_MEMORY_SCOPE_AGENT)
                       : 0.0f;
#pragma unroll
        for (int off = 1; off < 64; off <<= 1) w2 += __shfl_xor(w2, off);
        if (lane == 0) out[0] = w2 / (float)N;
    }
}

extern "C" void kernel_launch(void* const* d_in, const int* in_sizes, int n_in,
                              void* d_out, int out_size, void* d_ws, size_t ws_size,
                              hipStream_t stream) {
    const float* y = (const float*)d_in[0];
    int N = in_sizes[0] / DIM;                 // 8192
    uint8_t* ynq = (uint8_t*)d_ws;             // 2 MB (pair-interleaved fp8)
    float* posterm = (float*)((char*)d_ws + (size_t)N * DIM);   // 32 KB
    float* P = posterm + N;                    // 64*N f32 = 2 MB
    float* blockpart = P + (size_t)NT * N;     // NFIN f32
    unsigned* cnt = (unsigned*)(blockpart + NFIN);   // ticket counter
    unsigned* cnt2 = cnt + 1;                  // finalize counter
    float* out = (float*)d_out;

    hipMemsetAsync(cnt, 0, 2 * sizeof(unsigned), stream);   // per-call reset
    nt_normalize<<<N / 4, 256, 0, stream>>>(y, ynq, N);
    nt_gemm_red<<<T_TILES, 512, 0, stream>>>(ynq, P, posterm, blockpart,
                                             cnt, cnt2, out, N);
}